// Round 5
// baseline (1579.830 us; speedup 1.0000x reference)
//
#include <hip/hip_runtime.h>
#include <hip/hip_bf16.h>

#define NBLK 64
#define BS   128
#define GSZ  8192   // NBLK * BS

// ---------- wave-uniform register fetch helpers (lane index must be uniform) ----------
__device__ __forceinline__ int rl32(int v, int sl) {
    return __builtin_amdgcn_readlane(v, sl);
}
__device__ __forceinline__ double rl64(double v, int sl) {
    union { double d; unsigned u[2]; } a; a.d = v;
    unsigned lo = (unsigned)__builtin_amdgcn_readlane((int)a.u[0], sl);
    unsigned hi = (unsigned)__builtin_amdgcn_readlane((int)a.u[1], sl);
    union { unsigned u[2]; double d; } r; r.u[0] = lo; r.u[1] = hi;
    return r.d;
}
// monotone f64 -> u64 key; low 8 bits replaced by column (1..128) for
// np.argmin-style smallest-index tie-break. 8-bit mantissa truncation only
// merges values within 2^-45 relative — exact ties stay exact.
__device__ __forceinline__ unsigned long long pkey(double m, int col) {
    union { double d; unsigned long long u; } a; a.d = m;
    unsigned long long x = a.u;
    x = (x >> 63) ? ~x : (x | 0x8000000000000000ull);
    return (x & ~0xFFull) | (unsigned long long)(unsigned)col;
}

// rocPRIM-style wave64 min via DPP: row_shr 1/2/4/8 then row_bcast 15/31.
__device__ __forceinline__ unsigned wave_min_u32_dpp(unsigned x) {
    x = min(x, (unsigned)__builtin_amdgcn_update_dpp((int)x, (int)x, 0x111, 0xf, 0xf, false)); // row_shr:1
    x = min(x, (unsigned)__builtin_amdgcn_update_dpp((int)x, (int)x, 0x112, 0xf, 0xf, false)); // row_shr:2
    x = min(x, (unsigned)__builtin_amdgcn_update_dpp((int)x, (int)x, 0x114, 0xf, 0xf, false)); // row_shr:4
    x = min(x, (unsigned)__builtin_amdgcn_update_dpp((int)x, (int)x, 0x118, 0xf, 0xf, false)); // row_shr:8
    x = min(x, (unsigned)__builtin_amdgcn_update_dpp((int)x, (int)x, 0x142, 0xa, 0xf, false)); // row_bcast:15
    x = min(x, (unsigned)__builtin_amdgcn_update_dpp((int)x, (int)x, 0x143, 0xc, 0xf, false)); // row_bcast:31
    return (unsigned)__builtin_amdgcn_readlane((int)x, 63);
}

// exact u64-key min across the wave: hi32 DPP min + ballot; unique -> one
// dynamic readlane, else lo32 DPP min among hi-matching lanes.
__device__ __forceinline__ unsigned long long wave_min_key(unsigned long long k) {
    unsigned hi = (unsigned)(k >> 32);
    unsigned lo = (unsigned)k;
    unsigned mh = wave_min_u32_dpp(hi);
    unsigned long long msk = __ballot(hi == mh);
    unsigned lo_cand = (hi == mh) ? lo : 0xFFFFFFFFu;
    unsigned ml;
    if (__popcll(msk) == 1) {
        ml = (unsigned)__builtin_amdgcn_readlane((int)lo_cand, (int)__builtin_ctzll(msk));
    } else {
        ml = wave_min_u32_dpp(lo_cand);
    }
    return ((unsigned long long)mh << 32) | ml;
}

// ---------------------------------------------------------------------------
// Fused kernel (256 thr): sinkhorn (first 128 thr) -> { wave0: column-reduction
// seed + multi-source register-JV Dijkstra LAP, waves1-3: zero-fill the
// 128x8192 stripe } -> scatter ones.
// ---------------------------------------------------------------------------
__global__ __launch_bounds__(256) void k_fused(const float* __restrict__ w,
                                               const float* __restrict__ scale_p,
                                               float* __restrict__ out) {
    __shared__ float M[BS][BS + 1];   // [128][129] f32: conflict-free rows+cols
    __shared__ int   rowasg[BS];
    float* Mf = &M[0][0];

    const int b = blockIdx.x;
    const int t = threadIdx.x;
    const float scale = *scale_p;

    // ---- sinkhorn: P = sinkhorn(softmax(clamp(w*scale,-1,1)/3)) ----
    if (t < BS) {
        for (int r = 0; r < BS; ++r) {
            float x = w[((size_t)b * BS + r) * BS + t] * scale;
            x = fminf(fmaxf(x, -1.0f), 1.0f);
            M[r][t] = x / 3.0f;
        }
    }
    __syncthreads();
    if (t < BS) {   // softmax along rows (thread t owns row t)
        float mx = M[t][0];
        for (int c = 1; c < BS; ++c) mx = fmaxf(mx, M[t][c]);
        float s = 0.0f;
        for (int c = 0; c < BS; ++c) { float e = expf(M[t][c] - mx); M[t][c] = e; s += e; }
        float rs = 1.0f / s;
        for (int c = 0; c < BS; ++c) M[t][c] *= rs;
    }
    __syncthreads();
    for (int it = 0; it < 5; ++it) {
        if (t < BS) {
            float s = 0.0f;
            for (int c = 0; c < BS; ++c) s += M[t][c];
            float rs = 1.0f / s;
            for (int c = 0; c < BS; ++c) M[t][c] *= rs;
        }
        __syncthreads();
        if (t < BS) {
            float s = 0.0f;
            for (int r = 0; r < BS; ++r) s += M[r][t];
            float rs = 1.0f / s;
            for (int r = 0; r < BS; ++r) M[r][t] *= rs;
        }
        __syncthreads();
    }

    int pA = 0, pB = 0;   // row (1-based) assigned to cols t+1 / t+65; 0 = free

    if (t >= 64) {
        // ---- waves1-3: zero the 128-row output stripe (hidden under LAP) ----
        const int l = t - 64;   // 0..191
        float4 z = make_float4(0.f, 0.f, 0.f, 0.f);
        float4* o4 = reinterpret_cast<float4*>(out + (size_t)b * BS * GSZ);
        for (int k = l; k < BS * GSZ / 4; k += 192) o4[k] = z;
    } else {
        // ---- wave0: exact LAP on cost = -P, all state in registers ----
        const int jAcol = t + 1, jBcol = t + 65;
        double uA = 0.0, uB = 0.0, vA, vB;

        // column reduction seed: v[j] = min_i cost = -(max_i P); greedy assign
        {
            float cmA = Mf[t];      int raA = 0;
            float cmB = Mf[t + 64]; int raB = 0;
            for (int r = 1; r < BS; ++r) {
                float xA = Mf[r * (BS + 1) + t];
                if (xA > cmA) { cmA = xA; raA = r; }
                float xB = Mf[r * (BS + 1) + t + 64];
                if (xB > cmB) { cmB = xB; raB = r; }
            }
            vA = -(double)cmA; vB = -(double)cmB;
            rowasg[t] = 0x7FFFFFFF; rowasg[t + 64] = 0x7FFFFFFF;
            __threadfence_block();
            atomicMin(&rowasg[raA], jAcol);
            atomicMin(&rowasg[raB], jBcol);
            __threadfence_block();
            pA = (rowasg[raA] == jAcol) ? raA + 1 : 0;
            pB = (rowasg[raB] == jBcol) ? raB + 1 : 0;
        }

        // unassigned-row masks (rows 1..64 in un0, 65..128 in un1)
        unsigned long long un0 = __ballot(rowasg[t]      == 0x7FFFFFFF);
        unsigned long long un1 = __ballot(rowasg[t + 64] == 0x7FFFFFFF);

        // ---- multi-source Dijkstra phases (super-source SSP, exact) ----
        // Free rows all have u = 0 (never assigned). Each phase: init dist[j]
        // = min over free i of (-P[i][j]) - v[j] (src[j] = argmin row, way = 0),
        // then the verified e-maxx recursion (SUM-shifted: stored m == dist).
        for (int ph = 0; ph < 132 && (un0 | un1); ++ph) {
            double mA = 1e18, mB = 1e18;
            int srcA = 0, srcB = 0, wayA = 0, wayB = 0;

            // chunked column-parallel init over free rows (4 rows per chunk)
            unsigned long long e0 = un0, e1 = un1;
            while (e0 | e1) {
                int r0, r1, r2, r3;
                if (e0) { r0 = __builtin_ctzll(e0); e0 &= e0 - 1; }
                else    { r0 = 64 + __builtin_ctzll(e1); e1 &= e1 - 1; }
                r1 = r0; r2 = r0; r3 = r0;
                if (e0 | e1) { if (e0) { r1 = __builtin_ctzll(e0); e0 &= e0 - 1; }
                               else    { r1 = 64 + __builtin_ctzll(e1); e1 &= e1 - 1; } }
                if (e0 | e1) { if (e0) { r2 = __builtin_ctzll(e0); e0 &= e0 - 1; }
                               else    { r2 = 64 + __builtin_ctzll(e1); e1 &= e1 - 1; } }
                if (e0 | e1) { if (e0) { r3 = __builtin_ctzll(e0); e0 &= e0 - 1; }
                               else    { r3 = 64 + __builtin_ctzll(e1); e1 &= e1 - 1; } }
                float a0 = Mf[r0 * (BS + 1) + t], b0 = Mf[r0 * (BS + 1) + t + 64];
                float a1 = Mf[r1 * (BS + 1) + t], b1 = Mf[r1 * (BS + 1) + t + 64];
                float a2 = Mf[r2 * (BS + 1) + t], b2 = Mf[r2 * (BS + 1) + t + 64];
                float a3 = Mf[r3 * (BS + 1) + t], b3 = Mf[r3 * (BS + 1) + t + 64];
                double n0 = -(double)a0 - vA; if (n0 < mA) { mA = n0; srcA = r0 + 1; }
                double n1 = -(double)a1 - vA; if (n1 < mA) { mA = n1; srcA = r1 + 1; }
                double n2 = -(double)a2 - vA; if (n2 < mA) { mA = n2; srcA = r2 + 1; }
                double n3 = -(double)a3 - vA; if (n3 < mA) { mA = n3; srcA = r3 + 1; }
                double o0 = -(double)b0 - vB; if (o0 < mB) { mB = o0; srcB = r0 + 1; }
                double o1 = -(double)b1 - vB; if (o1 < mB) { mB = o1; srcB = r1 + 1; }
                double o2 = -(double)b2 - vB; if (o2 < mB) { mB = o2; srcB = r2 + 1; }
                double o3 = -(double)b3 - vB; if (o3 < mB) { mB = o3; srcB = r3 + 1; }
            }

            bool usedA = false, usedB = false;
            unsigned long long keyA = pkey(mA, jAcol), keyB = pkey(mB, jBcol);
            double SUM = 0.0;
            int jfree = 0;

            for (int guard = 0; guard < BS + 4; ++guard) {
                unsigned long long kw = wave_min_key(keyA < keyB ? keyA : keyB);
                const int  j1 = (int)(kw & 0xFFull);
                const int  sl = (j1 - 1) & 63;
                const bool hb = j1 > 64;

                double m_win = rl64(hb ? mB : mA, sl);   // exact f64 distance
                double delta = m_win - SUM;
                SUM = m_win;
                if (usedA) { uA += delta; vA -= delta; }
                if (usedB) { uB += delta; vB -= delta; }

                int pj = rl32(hb ? pB : pA, sl);
                if (pj == 0) { jfree = j1; break; }      // free column: augment
                double ui0 = rl64(hb ? uB : uA, sl);     // owner u (phase-start)
                if (t == sl) { if (hb) { usedB = true; keyB = ~0ull; }
                               else    { usedA = true; keyA = ~0ull; } }
                const int i0 = pj;
                float cA = Mf[(i0 - 1) * (BS + 1) + t];
                float cB = Mf[(i0 - 1) * (BS + 1) + t + 64];
                if (!usedA) {
                    double nd = (-(double)cA - ui0 - vA) + SUM;
                    if (nd < mA) { mA = nd; wayA = j1; keyA = pkey(nd, jAcol); }
                }
                if (!usedB) {
                    double nd = (-(double)cB - ui0 - vB) + SUM;
                    if (nd < mB) { mB = nd; wayB = j1; keyB = pkey(nd, jBcol); }
                }
            }

            if (!jfree) break;   // safety (cannot happen): bail, fail visibly

            // augment along way-chain; chain end (way==0) attaches source row
            int isrc = 0;
            int jc = jfree;
            for (int guard = 0; guard < BS + 4; ++guard) {
                const int  slc = (jc - 1) & 63;
                const bool hc  = jc > 64;
                int jp = rl32(hc ? wayB : wayA, slc);
                int nprow; double nu;
                if (jp == 0) {
                    isrc = rl32(hc ? srcB : srcA, slc);
                    nprow = isrc; nu = SUM;              // entering row: u = D*
                } else {
                    const int  slp = (jp - 1) & 63;
                    const bool hp  = jp > 64;
                    nprow = rl32(hp ? pB : pA, slp);
                    nu    = rl64(hp ? uB : uA, slp);
                }
                if (!hc) { if (t == slc) { pA = nprow; uA = nu; } }
                else     { if (t == slc) { pB = nprow; uB = nu; } }
                if (jp == 0) break;
                jc = jp;
            }
            if (isrc >= 1) {
                if (isrc <= 64) un0 &= ~(1ull << (isrc - 1));
                else            un1 &= ~(1ull << (isrc - 65));
            } else break;        // safety: malformed chain — fail visibly
        }
    }

    __syncthreads();   // stripe fully zeroed, assignment final

    if (t < 64) {
        const size_t base = (size_t)b * BS;
        if (pA >= 1) out[(base + (size_t)(pA - 1)) * GSZ + base + t]      = 1.0f;
        if (pB >= 1) out[(base + (size_t)(pB - 1)) * GSZ + base + t + 64] = 1.0f;
    }
}

extern "C" void kernel_launch(void* const* d_in, const int* in_sizes, int n_in,
                              void* d_out, int out_size, void* d_ws, size_t ws_size,
                              hipStream_t stream) {
    const float* w     = (const float*)d_in[0];
    const float* scale = (const float*)d_in[1];
    float* out = (float*)d_out;
    k_fused<<<NBLK, 256, 0, stream>>>(w, scale, out);
}

// Round 6
// 989.591 us; speedup vs baseline: 1.5964x; 1.5964x over previous
//
#include <hip/hip_runtime.h>
#include <hip/hip_bf16.h>

#define NBLK 64
#define BS   128
#define GSZ  8192   // NBLK * BS

// ---------- wave-uniform register fetch helpers (lane index must be uniform) ----------
__device__ __forceinline__ int rl32(int v, int sl) {
    return __builtin_amdgcn_readlane(v, sl);
}
__device__ __forceinline__ double rl64(double v, int sl) {
    union { double d; unsigned u[2]; } a; a.d = v;
    unsigned lo = (unsigned)__builtin_amdgcn_readlane((int)a.u[0], sl);
    unsigned hi = (unsigned)__builtin_amdgcn_readlane((int)a.u[1], sl);
    union { unsigned u[2]; double d; } r; r.u[0] = lo; r.u[1] = hi;
    return r.d;
}
// monotone f64 -> u64 key; low 8 bits = column (1..128): np.argmin tie-break.
__device__ __forceinline__ unsigned long long pkeyc(double m, int col) {
    union { double d; unsigned long long u; } a; a.d = m;
    unsigned long long x = a.u;
    x = (x >> 63) ? ~x : (x | 0x8000000000000000ull);
    return (x & ~0xFFull) | (unsigned long long)(unsigned)col;
}
// phase key: value bits [63:16] | owner-row pj [15:8] | col [7:0]. Matching is
// static within a phase, so pj rides in the key (saves a dependent readlane).
// 16-bit mantissa truncation = 2^-37 relative perturbation << optimum margin.
__device__ __forceinline__ unsigned long long pkey16(double m, int pj, int col) {
    union { double d; unsigned long long u; } a; a.d = m;
    unsigned long long x = a.u;
    x = (x >> 63) ? ~x : (x | 0x8000000000000000ull);
    return (x & ~0xFFFFull) | ((unsigned long long)(unsigned)pj << 8)
                            | (unsigned long long)(unsigned)col;
}

// rocPRIM-style wave64 min via DPP: row_shr 1/2/4/8 then row_bcast 15/31.
__device__ __forceinline__ unsigned wave_min_u32_dpp(unsigned x) {
    x = min(x, (unsigned)__builtin_amdgcn_update_dpp((int)x, (int)x, 0x111, 0xf, 0xf, false)); // row_shr:1
    x = min(x, (unsigned)__builtin_amdgcn_update_dpp((int)x, (int)x, 0x112, 0xf, 0xf, false)); // row_shr:2
    x = min(x, (unsigned)__builtin_amdgcn_update_dpp((int)x, (int)x, 0x114, 0xf, 0xf, false)); // row_shr:4
    x = min(x, (unsigned)__builtin_amdgcn_update_dpp((int)x, (int)x, 0x118, 0xf, 0xf, false)); // row_shr:8
    x = min(x, (unsigned)__builtin_amdgcn_update_dpp((int)x, (int)x, 0x142, 0xa, 0xf, false)); // row_bcast:15
    x = min(x, (unsigned)__builtin_amdgcn_update_dpp((int)x, (int)x, 0x143, 0xc, 0xf, false)); // row_bcast:31
    return (unsigned)__builtin_amdgcn_readlane((int)x, 63);
}
// exact u64-key min across the wave.
__device__ __forceinline__ unsigned long long wave_min_key(unsigned long long k) {
    unsigned hi = (unsigned)(k >> 32);
    unsigned lo = (unsigned)k;
    unsigned mh = wave_min_u32_dpp(hi);
    unsigned long long msk = __ballot(hi == mh);
    unsigned lo_cand = (hi == mh) ? lo : 0xFFFFFFFFu;
    unsigned ml;
    if (__popcll(msk) == 1) {
        ml = (unsigned)__builtin_amdgcn_readlane((int)lo_cand, (int)__builtin_ctzll(msk));
    } else {
        ml = wave_min_u32_dpp(lo_cand);
    }
    return ((unsigned long long)mh << 32) | ml;
}

// ---------------------------------------------------------------------------
// Fused kernel (256 thr): sinkhorn (first 128 thr) -> { wave0: col-reduction
// seed + ARR + multi-source multi-augment JV phases, waves1-3: zero-fill the
// 128x8192 stripe } -> scatter ones.
// ---------------------------------------------------------------------------
__global__ __launch_bounds__(256) void k_fused(const float* __restrict__ w,
                                               const float* __restrict__ scale_p,
                                               float* __restrict__ out) {
    __shared__ float M[BS][BS + 1];   // [128][129] f32: conflict-free rows+cols
    __shared__ int   rowasg[BS];
    float* Mf = &M[0][0];

    const int b = blockIdx.x;
    const int t = threadIdx.x;
    const float scale = *scale_p;

    // ---- sinkhorn: P = sinkhorn(softmax(clamp(w*scale,-1,1)/3)) ----
    if (t < BS) {
        for (int r = 0; r < BS; ++r) {
            float x = w[((size_t)b * BS + r) * BS + t] * scale;
            x = fminf(fmaxf(x, -1.0f), 1.0f);
            M[r][t] = x / 3.0f;
        }
    }
    __syncthreads();
    if (t < BS) {   // softmax along rows (thread t owns row t)
        float mx = M[t][0];
        for (int c = 1; c < BS; ++c) mx = fmaxf(mx, M[t][c]);
        float s = 0.0f;
        for (int c = 0; c < BS; ++c) { float e = expf(M[t][c] - mx); M[t][c] = e; s += e; }
        float rs = 1.0f / s;
        for (int c = 0; c < BS; ++c) M[t][c] *= rs;
    }
    __syncthreads();
    for (int it = 0; it < 5; ++it) {
        if (t < BS) {
            float s = 0.0f;
            for (int c = 0; c < BS; ++c) s += M[t][c];
            float rs = 1.0f / s;
            for (int c = 0; c < BS; ++c) M[t][c] *= rs;
        }
        __syncthreads();
        if (t < BS) {
            float s = 0.0f;
            for (int r = 0; r < BS; ++r) s += M[r][t];
            float rs = 1.0f / s;
            for (int r = 0; r < BS; ++r) M[r][t] *= rs;
        }
        __syncthreads();
    }

    int pA = 0, pB = 0;   // row (1-based) assigned to cols t+1 / t+65; 0 = free

    if (t >= 64) {
        // ---- waves1-3: zero the 128-row output stripe (hidden under LAP) ----
        const int l = t - 64;   // 0..191
        float4 z = make_float4(0.f, 0.f, 0.f, 0.f);
        float4* o4 = reinterpret_cast<float4*>(out + (size_t)b * BS * GSZ);
        for (int k = l; k < BS * GSZ / 4; k += 192) o4[k] = z;
    } else {
        // ---- wave0: exact LAP on cost = -P, all state in registers ----
        const int jAcol = t + 1, jBcol = t + 65;
        double uA = 0.0, uB = 0.0, vA, vB;

        // column reduction seed: v[j] = min_i cost = -(max_i P); greedy assign
        {
            float cmA = Mf[t];      int raA = 0;
            float cmB = Mf[t + 64]; int raB = 0;
            for (int r = 1; r < BS; ++r) {
                float xA = Mf[r * (BS + 1) + t];
                if (xA > cmA) { cmA = xA; raA = r; }
                float xB = Mf[r * (BS + 1) + t + 64];
                if (xB > cmB) { cmB = xB; raB = r; }
            }
            vA = -(double)cmA; vB = -(double)cmB;
            rowasg[t] = 0x7FFFFFFF; rowasg[t + 64] = 0x7FFFFFFF;
            __threadfence_block();
            atomicMin(&rowasg[raA], jAcol);
            atomicMin(&rowasg[raB], jBcol);
            __threadfence_block();
            pA = (rowasg[raA] == jAcol) ? raA + 1 : 0;
            pB = (rowasg[raB] == jBcol) ? raB + 1 : 0;
        }

        // unassigned-row masks (rows 1..64 in un0, 65..128 in un1)
        unsigned long long un0 = __ballot(rowasg[t]      == 0x7FFFFFFF);
        unsigned long long un1 = __ballot(rowasg[t + 64] == 0x7FFFFFFF);

        // ---- ARR: augmenting row reduction (lapjv), capped — verified in R4.
        for (int steps = 0; (un0 | un1) && steps < 512; ++steps) {
            int i;
            if (un0) i = __builtin_ctzll(un0) + 1;
            else     i = __builtin_ctzll(un1) + 65;

            double dA = -(double)Mf[(i - 1) * (BS + 1) + t]      - vA;
            double dB = -(double)Mf[(i - 1) * (BS + 1) + t + 64] - vB;
            unsigned long long kA = pkeyc(dA, jAcol), kB = pkeyc(dB, jBcol);

            unsigned long long k1 = wave_min_key(kA < kB ? kA : kB);
            const int  j1  = (int)(k1 & 0xFFull);
            const int  sl1 = (j1 - 1) & 63;
            const bool h1  = j1 > 64;
            double u1 = rl64(h1 ? dB : dA, sl1);

            unsigned long long kA2 = (jAcol == j1) ? ~0ull : kA;
            unsigned long long kB2 = (jBcol == j1) ? ~0ull : kB;
            unsigned long long k2 = wave_min_key(kA2 < kB2 ? kA2 : kB2);
            const int  sl2 = ((int)(k2 & 0xFFull) - 1) & 63;
            const bool h2  = (int)(k2 & 0xFFull) > 64;
            double u2 = rl64(h2 ? dB : dA, sl2);

            int i1 = rl32(h1 ? pB : pA, sl1);   // previous owner of j1 (0 = none)

            if (t == sl1) {
                if (h1) { pB = i; uB = u2; if (u1 < u2) vB -= (u2 - u1); }
                else    { pA = i; uA = u2; if (u1 < u2) vA -= (u2 - u1); }
            }
            if (i <= 64) un0 &= ~(1ull << (i - 1)); else un1 &= ~(1ull << (i - 65));
            if (i1 > 0) {
                if (i1 <= 64) un0 |= 1ull << (i1 - 1); else un1 |= 1ull << (i1 - 65);
            }
        }

        // ---- multi-source multi-augment Dijkstra phases (exact JV/HK hybrid).
        // All free rows share u = U_FREE (scalar). Each phase: super-source
        // Dijkstra until ALL free columns popped (incremental relabel; popped
        // free columns join the v-decrement set), then augment a maximal
        // pop-order set of vertex-disjoint tight paths. Feasibility+tightness
        // => final matching is the unique optimum.
        double U_FREE = 0.0;
        for (int ph = 0; ph < 132 && (un0 | un1); ++ph) {
            const int fre = __popcll(un0) + __popcll(un1);
            double mA = 1e18, mB = 1e18;
            int srcA = 0, srcB = 0, wayA = 0, wayB = 0;

            // chunked column-parallel init over free rows (4 rows per chunk)
            unsigned long long e0 = un0, e1 = un1;
            while (e0 | e1) {
                int r0, r1, r2, r3;
                if (e0) { r0 = __builtin_ctzll(e0); e0 &= e0 - 1; }
                else    { r0 = 64 + __builtin_ctzll(e1); e1 &= e1 - 1; }
                r1 = r0; r2 = r0; r3 = r0;
                if (e0 | e1) { if (e0) { r1 = __builtin_ctzll(e0); e0 &= e0 - 1; }
                               else    { r1 = 64 + __builtin_ctzll(e1); e1 &= e1 - 1; } }
                if (e0 | e1) { if (e0) { r2 = __builtin_ctzll(e0); e0 &= e0 - 1; }
                               else    { r2 = 64 + __builtin_ctzll(e1); e1 &= e1 - 1; } }
                if (e0 | e1) { if (e0) { r3 = __builtin_ctzll(e0); e0 &= e0 - 1; }
                               else    { r3 = 64 + __builtin_ctzll(e1); e1 &= e1 - 1; } }
                float a0 = Mf[r0 * (BS + 1) + t], b0 = Mf[r0 * (BS + 1) + t + 64];
                float a1 = Mf[r1 * (BS + 1) + t], b1 = Mf[r1 * (BS + 1) + t + 64];
                float a2 = Mf[r2 * (BS + 1) + t], b2 = Mf[r2 * (BS + 1) + t + 64];
                float a3 = Mf[r3 * (BS + 1) + t], b3 = Mf[r3 * (BS + 1) + t + 64];
                double n0 = -(double)a0 - U_FREE - vA; if (n0 < mA) { mA = n0; srcA = r0 + 1; }
                double n1 = -(double)a1 - U_FREE - vA; if (n1 < mA) { mA = n1; srcA = r1 + 1; }
                double n2 = -(double)a2 - U_FREE - vA; if (n2 < mA) { mA = n2; srcA = r2 + 1; }
                double n3 = -(double)a3 - U_FREE - vA; if (n3 < mA) { mA = n3; srcA = r3 + 1; }
                double o0 = -(double)b0 - U_FREE - vB; if (o0 < mB) { mB = o0; srcB = r0 + 1; }
                double o1 = -(double)b1 - U_FREE - vB; if (o1 < mB) { mB = o1; srcB = r1 + 1; }
                double o2 = -(double)b2 - U_FREE - vB; if (o2 < mB) { mB = o2; srcB = r2 + 1; }
                double o3 = -(double)b3 - U_FREE - vB; if (o3 < mB) { mB = o3; srcB = r3 + 1; }
            }

            bool usedA = false, usedB = false;
            unsigned long long keyA = pkey16(mA, pA, jAcol);
            unsigned long long keyB = pkey16(mB, pB, jBcol);
            double SUM = 0.0;
            int nf = 0;                 // free columns popped, in pop order
            int fregLo = 0, fregHi = 0; // lane q (or q-64) holds q-th target

            for (int pop = 0; pop < BS && nf < fre; ++pop) {
                unsigned long long kw = wave_min_key(keyA < keyB ? keyA : keyB);
                if (kw == ~0ull) break;                  // safety
                const int  j1 = (int)(kw & 0xFFull);
                const int  pj = (int)((kw >> 8) & 0xFFull);
                const int  sl = (j1 - 1) & 63;
                const bool hb = j1 > 64;

                double m_win = rl64(hb ? mB : mA, sl);   // exact f64 distance
                double delta = m_win - SUM;
                SUM = m_win;
                if (usedA) { uA += delta; vA -= delta; }  // free used: v-only
                if (usedB) { uB += delta; vB -= delta; }  // meaningful (u dead)
                if (t == sl) { if (hb) { usedB = true; keyB = ~0ull; }
                               else    { usedA = true; keyA = ~0ull; } }

                if (pj == 0) {                           // free column popped
                    if (nf < 64) { if (t == nf)      fregLo = j1; }
                    else         { if (t == nf - 64) fregHi = j1; }
                    ++nf;
                    continue;
                }
                double ui0 = rl64(hb ? uB : uA, sl);     // owner's current u
                const int i0 = pj;
                float cA = Mf[(i0 - 1) * (BS + 1) + t];
                float cB = Mf[(i0 - 1) * (BS + 1) + t + 64];
                if (!usedA) {
                    double nd = (-(double)cA - ui0 - vA) + SUM;
                    if (nd < mA) { mA = nd; wayA = j1; keyA = pkey16(nd, pA, jAcol); }
                }
                if (!usedB) {
                    double nd = (-(double)cB - ui0 - vB) + SUM;
                    if (nd < mB) { mB = nd; wayB = j1; keyB = pkey16(nd, pB, jBcol); }
                }
            }

            if (nf == 0) break;   // safety (cannot happen): bail, fail visibly

            // ---- vertex-disjoint augment, pop-order priority ----
            unsigned long long ccol0 = 0, ccol1 = 0;   // consumed columns
            unsigned long long csr0 = 0, csr1 = 0;     // consumed source rows
            for (int q = 0; q < nf; ++q) {
                const int target = (q < 64) ? rl32(fregLo, q) : rl32(fregHi, q - 64);
                // validation walk
                int jc = target, src = 0; bool ok = true;
                for (int g = 0; g < BS + 2; ++g) {
                    const int  slc = (jc - 1) & 63;
                    const bool hc  = jc > 64;
                    if (((hc ? ccol1 : ccol0) >> slc) & 1ull) { ok = false; break; }
                    int jp = rl32(hc ? wayB : wayA, slc);
                    if (jp == 0) {
                        src = rl32(hc ? srcB : srcA, slc);
                        const int  sls = (src - 1) & 63;
                        const bool hs  = src > 64;
                        if (((hs ? csr1 : csr0) >> sls) & 1ull) ok = false;
                        break;
                    }
                    jc = jp;
                }
                if (!ok || src < 1) continue;
                // apply walk: child takes parent's row (+its u); end -> source
                int jc2 = target;
                for (int g = 0; g < BS + 2; ++g) {
                    const int  slc = (jc2 - 1) & 63;
                    const bool hc  = jc2 > 64;
                    if (hc) ccol1 |= 1ull << slc; else ccol0 |= 1ull << slc;
                    int jp = rl32(hc ? wayB : wayA, slc);
                    int nprow; double nu;
                    if (jp == 0) { nprow = src; nu = U_FREE + SUM; }
                    else {
                        const int  slp = (jp - 1) & 63;
                        const bool hp  = jp > 64;
                        nprow = rl32(hp ? pB : pA, slp);
                        nu    = rl64(hp ? uB : uA, slp);
                    }
                    if (!hc) { if (t == slc) { pA = nprow; uA = nu; } }
                    else     { if (t == slc) { pB = nprow; uB = nu; } }
                    if (jp == 0) break;
                    jc2 = jp;
                }
                { const int sls = (src - 1) & 63;
                  if (src > 64) csr1 |= 1ull << sls; else csr0 |= 1ull << sls; }
                if (src <= 64) un0 &= ~(1ull << (src - 1));
                else           un1 &= ~(1ull << (src - 65));
            }
            U_FREE += SUM;   // still-free rows carry u = U_FREE into next phase
        }
    }

    __syncthreads();   // stripe fully zeroed, assignment final

    if (t < 64) {
        const size_t base = (size_t)b * BS;
        if (pA >= 1) out[(base + (size_t)(pA - 1)) * GSZ + base + t]      = 1.0f;
        if (pB >= 1) out[(base + (size_t)(pB - 1)) * GSZ + base + t + 64] = 1.0f;
    }
}

extern "C" void kernel_launch(void* const* d_in, const int* in_sizes, int n_in,
                              void* d_out, int out_size, void* d_ws, size_t ws_size,
                              hipStream_t stream) {
    const float* w     = (const float*)d_in[0];
    const float* scale = (const float*)d_in[1];
    float* out = (float*)d_out;
    k_fused<<<NBLK, 256, 0, stream>>>(w, scale, out);
}

// Round 7
// 837.936 us; speedup vs baseline: 1.8854x; 1.1810x over previous
//
#include <hip/hip_runtime.h>
#include <hip/hip_bf16.h>

#define NBLK 64
#define BS   128
#define GSZ  8192   // NBLK * BS

// ---------- wave-uniform register fetch helpers (lane index must be uniform) ----------
__device__ __forceinline__ int rl32(int v, int sl) {
    return __builtin_amdgcn_readlane(v, sl);
}
__device__ __forceinline__ double rl64(double v, int sl) {
    union { double d; unsigned u[2]; } a; a.d = v;
    unsigned lo = (unsigned)__builtin_amdgcn_readlane((int)a.u[0], sl);
    unsigned hi = (unsigned)__builtin_amdgcn_readlane((int)a.u[1], sl);
    union { unsigned u[2]; double d; } r; r.u[0] = lo; r.u[1] = hi;
    return r.d;
}
// phase key: value bits [63:16] | owner-row pj [15:8] | col [7:0]. Matching is
// static within a phase, so pj rides in the key (saves a dependent readlane).
// 16-bit truncation only perturbs the POP ORDER by 2^-37 relative; dual updates
// use the exact f64 (rl64) value, so invariants hold to f64 rounding as before.
__device__ __forceinline__ unsigned long long pkey16(double m, int pj, int col) {
    union { double d; unsigned long long u; } a; a.d = m;
    unsigned long long x = a.u;
    x = (x >> 63) ? ~x : (x | 0x8000000000000000ull);
    return (x & ~0xFFFFull) | ((unsigned long long)(unsigned)pj << 8)
                            | (unsigned long long)(unsigned)col;
}

// rocPRIM-style wave64 min via DPP: row_shr 1/2/4/8 then row_bcast 15/31.
__device__ __forceinline__ unsigned wave_min_u32_dpp(unsigned x) {
    x = min(x, (unsigned)__builtin_amdgcn_update_dpp((int)x, (int)x, 0x111, 0xf, 0xf, false)); // row_shr:1
    x = min(x, (unsigned)__builtin_amdgcn_update_dpp((int)x, (int)x, 0x112, 0xf, 0xf, false)); // row_shr:2
    x = min(x, (unsigned)__builtin_amdgcn_update_dpp((int)x, (int)x, 0x114, 0xf, 0xf, false)); // row_shr:4
    x = min(x, (unsigned)__builtin_amdgcn_update_dpp((int)x, (int)x, 0x118, 0xf, 0xf, false)); // row_shr:8
    x = min(x, (unsigned)__builtin_amdgcn_update_dpp((int)x, (int)x, 0x142, 0xa, 0xf, false)); // row_bcast:15
    x = min(x, (unsigned)__builtin_amdgcn_update_dpp((int)x, (int)x, 0x143, 0xc, 0xf, false)); // row_bcast:31
    return (unsigned)__builtin_amdgcn_readlane((int)x, 63);
}
// exact u64-key min across the wave.
__device__ __forceinline__ unsigned long long wave_min_key(unsigned long long k) {
    unsigned hi = (unsigned)(k >> 32);
    unsigned lo = (unsigned)k;
    unsigned mh = wave_min_u32_dpp(hi);
    unsigned long long msk = __ballot(hi == mh);
    unsigned lo_cand = (hi == mh) ? lo : 0xFFFFFFFFu;
    unsigned ml;
    if (__popcll(msk) == 1) {
        ml = (unsigned)__builtin_amdgcn_readlane((int)lo_cand, (int)__builtin_ctzll(msk));
    } else {
        ml = wave_min_u32_dpp(lo_cand);
    }
    return ((unsigned long long)mh << 32) | ml;
}

// ---------------------------------------------------------------------------
// Fused kernel (256 thr): sinkhorn (first 128 thr) -> { wave0: col-reduction
// seed + Jacobi-parallel ARR + register-JV Dijkstra, waves1-3: zero-fill the
// 128x8192 stripe } -> scatter ones.
// ---------------------------------------------------------------------------
__global__ __launch_bounds__(256) void k_fused(const float* __restrict__ w,
                                               const float* __restrict__ scale_p,
                                               float* __restrict__ out) {
    __shared__ float    M[BS][BS + 1];   // [128][129] f32: conflict-free rows+cols
    __shared__ int      rowasg[BS];
    __shared__ double   vldS[BS];
    __shared__ unsigned bidS[BS];
    __shared__ int      wrowS[BS];
    __shared__ double   wu2S[BS];
    __shared__ double   wduS[BS];
    float* Mf = &M[0][0];

    const int b = blockIdx.x;
    const int t = threadIdx.x;
    const float scale = *scale_p;

    // ---- sinkhorn: P = sinkhorn(softmax(clamp(w*scale,-1,1)/3)) ----
    if (t < BS) {
        for (int r = 0; r < BS; ++r) {
            float x = w[((size_t)b * BS + r) * BS + t] * scale;
            x = fminf(fmaxf(x, -1.0f), 1.0f);
            M[r][t] = x / 3.0f;
        }
    }
    __syncthreads();
    if (t < BS) {   // softmax along rows (thread t owns row t)
        float mx = M[t][0];
        for (int c = 1; c < BS; ++c) mx = fmaxf(mx, M[t][c]);
        float s = 0.0f;
        for (int c = 0; c < BS; ++c) { float e = expf(M[t][c] - mx); M[t][c] = e; s += e; }
        float rs = 1.0f / s;
        for (int c = 0; c < BS; ++c) M[t][c] *= rs;
    }
    __syncthreads();
    for (int it = 0; it < 5; ++it) {
        if (t < BS) {
            float s = 0.0f;
            for (int c = 0; c < BS; ++c) s += M[t][c];
            float rs = 1.0f / s;
            for (int c = 0; c < BS; ++c) M[t][c] *= rs;
        }
        __syncthreads();
        if (t < BS) {
            float s = 0.0f;
            for (int r = 0; r < BS; ++r) s += M[r][t];
            float rs = 1.0f / s;
            for (int r = 0; r < BS; ++r) M[r][t] *= rs;
        }
        __syncthreads();
    }

    int pA = 0, pB = 0;   // row (1-based) assigned to cols t+1 / t+65; 0 = free

    if (t >= 64) {
        // ---- waves1-3: zero the 128-row output stripe (hidden under LAP) ----
        const int l = t - 64;   // 0..191
        float4 z = make_float4(0.f, 0.f, 0.f, 0.f);
        float4* o4 = reinterpret_cast<float4*>(out + (size_t)b * BS * GSZ);
        for (int k = l; k < BS * GSZ / 4; k += 192) o4[k] = z;
    } else {
        // ---- wave0: exact LAP on cost = -P, all state in registers ----
        const int jAcol = t + 1, jBcol = t + 65;
        double uA = 0.0, uB = 0.0, vA, vB;

        // column reduction seed: v[j] = min_i cost = -(max_i P); greedy assign
        {
            float cmA = Mf[t];      int raA = 0;
            float cmB = Mf[t + 64]; int raB = 0;
            for (int r = 1; r < BS; ++r) {
                float xA = Mf[r * (BS + 1) + t];
                if (xA > cmA) { cmA = xA; raA = r; }
                float xB = Mf[r * (BS + 1) + t + 64];
                if (xB > cmB) { cmB = xB; raB = r; }
            }
            vA = -(double)cmA; vB = -(double)cmB;
            rowasg[t] = 0x7FFFFFFF; rowasg[t + 64] = 0x7FFFFFFF;
            __threadfence_block();
            atomicMin(&rowasg[raA], jAcol);
            atomicMin(&rowasg[raB], jBcol);
            __threadfence_block();
            pA = (rowasg[raA] == jAcol) ? raA + 1 : 0;
            pB = (rowasg[raB] == jBcol) ? raB + 1 : 0;
        }

        // unassigned-row masks (rows 1..64 in un0, 65..128 in un1)
        unsigned long long un0 = __ballot(rowasg[t]      == 0x7FFFFFFF);
        unsigned long long un1 = __ballot(rowasg[t + 64] == 0x7FFFFFFF);

        // ---- Jacobi-parallel ARR (auction-style). Invariants each round:
        // v only decreases (all rows stay feasible at u=0); winners assigned
        // TIGHT (u=u2, v[j1]-=u2-u1) and feasible even under simultaneous
        // column updates. Winner per column unique & order-independent
        // (packed bid includes row id) => deterministic. Any stall -> break;
        // the exact Dijkstra below finishes from any such state.
        {
            volatile double*   vl   = vldS;
            volatile unsigned* bidv = bidS;
            volatile int*      wrow = wrowS;
            volatile double*   wu2  = wu2S;
            volatile double*   wdu  = wduS;
            volatile int*      asg  = rowasg;   // reuse seed scratch
            int stall = 0;
            for (int rd = 0; rd < 24 && (un0 | un1); ++rd) {
                vl[t] = vA; vl[t + 64] = vB;
                bidv[t] = 0u; bidv[t + 64] = 0u;
                wrow[t] = 0;  wrow[t + 64] = 0;
                const bool fA = (un0 >> t) & 1ull;   // row t+1 free?
                const bool fB = (un1 >> t) & 1ull;   // row t+65 free?
                double u1A = 1e18, u2A = 1e18, u1B = 1e18, u2B = 1e18;
                int j1A = 1, j1B = 1;
                for (int c = 0; c < BS; ++c) {
                    double vv = vl[c];
                    float  a  = Mf[t * (BS + 1) + c];
                    float  bq = Mf[(t + 64) * (BS + 1) + c];
                    double da = -(double)a  - vv;
                    double db = -(double)bq - vv;
                    if (fA) { if (da < u1A) { u2A = u1A; u1A = da; j1A = c + 1; }
                              else if (da < u2A) u2A = da; }
                    if (fB) { if (db < u1B) { u2B = u1B; u1B = db; j1B = c + 1; }
                              else if (db < u2B) u2B = db; }
                }
                unsigned pkA = 0, pkB = 0;
                if (fA) { unsigned ib = __float_as_uint((float)(u2A - u1A));
                          pkA = (((ib >> 7) + 1u) << 7) | (unsigned)t;
                          atomicMax(&bidS[j1A - 1], pkA); }
                if (fB) { unsigned ib = __float_as_uint((float)(u2B - u1B));
                          pkB = (((ib >> 7) + 1u) << 7) | (unsigned)(t + 64);
                          atomicMax(&bidS[j1B - 1], pkB); }
                // winners publish (unique: packed bid embeds row id)
                if (fA && bidv[j1A - 1] == pkA) {
                    wrow[j1A - 1] = t + 1;  wu2[j1A - 1] = u2A; wdu[j1A - 1] = u2A - u1A;
                }
                if (fB && bidv[j1B - 1] == pkB) {
                    wrow[j1B - 1] = t + 65; wu2[j1B - 1] = u2B; wdu[j1B - 1] = u2B - u1B;
                }
                // column owners apply
                { int wa = wrow[t];
                  if (wa > 0) { pA = wa; uA = wu2[t];      vA -= wdu[t]; } }
                { int wb = wrow[t + 64];
                  if (wb > 0) { pB = wb; uB = wu2[t + 64]; vB -= wdu[t + 64]; } }
                // recompute free-row masks from the matching
                asg[t] = 0; asg[t + 64] = 0;
                if (pA > 0) asg[pA - 1] = 1;
                if (pB > 0) asg[pB - 1] = 1;
                unsigned long long n0 = __ballot(asg[t] == 0);
                unsigned long long n1 = __ballot(asg[t + 64] == 0);
                int oldf = __popcll(un0) + __popcll(un1);
                int newf = __popcll(n0) + __popcll(n1);
                un0 = n0; un1 = n1;
                if (newf < oldf) stall = 0;
                else if (++stall >= 2) break;
            }
        }

        // ---- single-source Dijkstra phases (R4-verified recursion, pj-in-key) ----
        while (un0 | un1) {
            int i;
            if (un0) { int r = __builtin_ctzll(un0); un0 &= un0 - 1; i = r + 1; }
            else     { int r = __builtin_ctzll(un1); un1 &= un1 - 1; i = r + 65; }

            bool usedA = false, usedB = false;
            double mA = 1e18, mB = 1e18, SUM = 0.0;   // stored m = true_minv + SUM
            unsigned long long keyA = ~0ull, keyB = ~0ull;
            int wayA = 0, wayB = 0;
            int i0 = i, j0 = 0;
            double ui0 = 0.0;                          // free row: u = 0

            for (int guard = 0; guard <= BS + 2; ++guard) {
                // scan row i0 against this lane's two columns
                float cAv = Mf[(i0 - 1) * (BS + 1) + t];
                float cBv = Mf[(i0 - 1) * (BS + 1) + t + 64];
                if (!usedA) {
                    double nd = (-(double)cAv - ui0 - vA) + SUM;
                    if (nd < mA) { mA = nd; wayA = j0; keyA = pkey16(nd, pA, jAcol); }
                }
                if (!usedB) {
                    double nd = (-(double)cBv - ui0 - vB) + SUM;
                    if (nd < mB) { mB = nd; wayB = j0; keyB = pkey16(nd, pB, jBcol); }
                }
                unsigned long long kw = wave_min_key(keyA < keyB ? keyA : keyB);
                if (kw == ~0ull) break;                  // safety: fail visibly
                const int  j1 = (int)(kw & 0xFFull);
                const int  pj = (int)((kw >> 8) & 0xFFull);
                const int  sl = (j1 - 1) & 63;
                const bool hb = j1 > 64;

                double m_win = rl64(hb ? mB : mA, sl);   // exact f64 min value
                double delta = m_win - SUM;
                SUM = m_win;
                if (usedA) { uA += delta; vA -= delta; }
                if (usedB) { uB += delta; vB -= delta; }

                j0 = j1;
                if (pj == 0) break;                      // free column: augment
                ui0 = rl64(hb ? uB : uA, sl);            // owner u (pre-mark)
                i0 = pj;
                if (t == sl) { if (hb) { usedB = true; keyB = ~0ull; }
                               else    { usedA = true; keyA = ~0ull; } }
            }

            // augment along way-chain; duals u travel with their rows
            int jc = j0;
            for (int guard = 0; guard <= BS + 2; ++guard) {
                const int  slc = (jc - 1) & 63;
                const bool hc  = jc > 64;
                int jp = rl32(hc ? wayB : wayA, slc);
                int nprow; double nu;
                if (jp == 0) { nprow = i; nu = SUM; }    // start row: u was 0
                else {
                    const int  slp = (jp - 1) & 63;
                    const bool hp  = jp > 64;
                    nprow = rl32(hp ? pB : pA, slp);
                    nu    = rl64(hp ? uB : uA, slp);
                }
                if (!hc) { if (t == slc) { pA = nprow; uA = nu; } }
                else     { if (t == slc) { pB = nprow; uB = nu; } }
                if (jp == 0) break;
                jc = jp;
            }
        }
    }

    __syncthreads();   // stripe fully zeroed, assignment final

    if (t < 64) {
        const size_t base = (size_t)b * BS;
        if (pA >= 1) out[(base + (size_t)(pA - 1)) * GSZ + base + t]      = 1.0f;
        if (pB >= 1) out[(base + (size_t)(pB - 1)) * GSZ + base + t + 64] = 1.0f;
    }
}

extern "C" void kernel_launch(void* const* d_in, const int* in_sizes, int n_in,
                              void* d_out, int out_size, void* d_ws, size_t ws_size,
                              hipStream_t stream) {
    const float* w     = (const float*)d_in[0];
    const float* scale = (const float*)d_in[1];
    float* out = (float*)d_out;
    k_fused<<<NBLK, 256, 0, stream>>>(w, scale, out);
}

// Round 8
// 753.968 us; speedup vs baseline: 2.0954x; 1.1114x over previous
//
#include <hip/hip_runtime.h>
#include <hip/hip_bf16.h>

#define NBLK 64
#define BS   128
#define GSZ  8192   // NBLK * BS

// ---------- wave-uniform register fetch helpers (lane index must be uniform) ----------
__device__ __forceinline__ int rl32(int v, int sl) {
    return __builtin_amdgcn_readlane(v, sl);
}
__device__ __forceinline__ double rl64(double v, int sl) {
    union { double d; unsigned u[2]; } a; a.d = v;
    unsigned lo = (unsigned)__builtin_amdgcn_readlane((int)a.u[0], sl);
    unsigned hi = (unsigned)__builtin_amdgcn_readlane((int)a.u[1], sl);
    union { unsigned u[2]; double d; } r; r.u[0] = lo; r.u[1] = hi;
    return r.d;
}
// ARR key: monotone f64 -> u64, low 8 bits = column (np.argmin tie-break).
__device__ __forceinline__ unsigned long long pkeyc(double m, int col) {
    union { double d; unsigned long long u; } a; a.d = m;
    unsigned long long x = a.u;
    x = (x >> 63) ? ~x : (x | 0x8000000000000000ull);
    return (x & ~0xFFull) | (unsigned long long)(unsigned)col;
}
// Dijkstra key: value bits [63:16] | owner-row pj [15:8] | col [7:0]. The
// matching is static within a phase, so pj rides in the key — the winning
// column's owner, its dual (rl64), and the next row ds_read all issue right
// after the argmin with no dependent readlane. 16-bit truncation perturbs
// pop order only at 2^-37 relative; dual updates use exact f64 values.
__device__ __forceinline__ unsigned long long pkey16(double m, int pj, int col) {
    union { double d; unsigned long long u; } a; a.d = m;
    unsigned long long x = a.u;
    x = (x >> 63) ? ~x : (x | 0x8000000000000000ull);
    return (x & ~0xFFFFull) | ((unsigned long long)(unsigned)pj << 8)
                            | (unsigned long long)(unsigned)col;
}

// rocPRIM-style wave64 min via DPP: row_shr 1/2/4/8 then row_bcast 15/31.
__device__ __forceinline__ unsigned wave_min_u32_dpp(unsigned x) {
    x = min(x, (unsigned)__builtin_amdgcn_update_dpp((int)x, (int)x, 0x111, 0xf, 0xf, false)); // row_shr:1
    x = min(x, (unsigned)__builtin_amdgcn_update_dpp((int)x, (int)x, 0x112, 0xf, 0xf, false)); // row_shr:2
    x = min(x, (unsigned)__builtin_amdgcn_update_dpp((int)x, (int)x, 0x114, 0xf, 0xf, false)); // row_shr:4
    x = min(x, (unsigned)__builtin_amdgcn_update_dpp((int)x, (int)x, 0x118, 0xf, 0xf, false)); // row_shr:8
    x = min(x, (unsigned)__builtin_amdgcn_update_dpp((int)x, (int)x, 0x142, 0xa, 0xf, false)); // row_bcast:15
    x = min(x, (unsigned)__builtin_amdgcn_update_dpp((int)x, (int)x, 0x143, 0xc, 0xf, false)); // row_bcast:31
    return (unsigned)__builtin_amdgcn_readlane((int)x, 63);
}
// exact u64-key min across the wave.
__device__ __forceinline__ unsigned long long wave_min_key(unsigned long long k) {
    unsigned hi = (unsigned)(k >> 32);
    unsigned lo = (unsigned)k;
    unsigned mh = wave_min_u32_dpp(hi);
    unsigned long long msk = __ballot(hi == mh);
    unsigned lo_cand = (hi == mh) ? lo : 0xFFFFFFFFu;
    unsigned ml;
    if (__popcll(msk) == 1) {
        ml = (unsigned)__builtin_amdgcn_readlane((int)lo_cand, (int)__builtin_ctzll(msk));
    } else {
        ml = wave_min_u32_dpp(lo_cand);
    }
    return ((unsigned long long)mh << 32) | ml;
}

// ---------------------------------------------------------------------------
// Fused kernel (256 thr): sinkhorn (first 128 thr) -> { wave0: col-reduction
// seed + sequential ARR + register-JV Dijkstra (pj-in-key), waves1-3:
// zero-fill the 128x8192 stripe } -> scatter ones.
// ---------------------------------------------------------------------------
__global__ __launch_bounds__(256) void k_fused(const float* __restrict__ w,
                                               const float* __restrict__ scale_p,
                                               float* __restrict__ out) {
    __shared__ float M[BS][BS + 1];   // [128][129] f32: conflict-free rows+cols
    __shared__ int   rowasg[BS];
    float* Mf = &M[0][0];

    const int b = blockIdx.x;
    const int t = threadIdx.x;
    const float scale = *scale_p;

    // ---- sinkhorn: P = sinkhorn(softmax(clamp(w*scale,-1,1)/3)) ----
    if (t < BS) {
        for (int r = 0; r < BS; ++r) {
            float x = w[((size_t)b * BS + r) * BS + t] * scale;
            x = fminf(fmaxf(x, -1.0f), 1.0f);
            M[r][t] = x / 3.0f;
        }
    }
    __syncthreads();
    if (t < BS) {   // softmax along rows (thread t owns row t)
        float mx = M[t][0];
        for (int c = 1; c < BS; ++c) mx = fmaxf(mx, M[t][c]);
        float s = 0.0f;
        for (int c = 0; c < BS; ++c) { float e = expf(M[t][c] - mx); M[t][c] = e; s += e; }
        float rs = 1.0f / s;
        for (int c = 0; c < BS; ++c) M[t][c] *= rs;
    }
    __syncthreads();
    for (int it = 0; it < 5; ++it) {
        if (t < BS) {
            float s = 0.0f;
            for (int c = 0; c < BS; ++c) s += M[t][c];
            float rs = 1.0f / s;
            for (int c = 0; c < BS; ++c) M[t][c] *= rs;
        }
        __syncthreads();
        if (t < BS) {
            float s = 0.0f;
            for (int r = 0; r < BS; ++r) s += M[r][t];
            float rs = 1.0f / s;
            for (int r = 0; r < BS; ++r) M[r][t] *= rs;
        }
        __syncthreads();
    }

    int pA = 0, pB = 0;   // row (1-based) assigned to cols t+1 / t+65; 0 = free

    if (t >= 64) {
        // ---- waves1-3: zero the 128-row output stripe (hidden under LAP) ----
        const int l = t - 64;   // 0..191
        float4 z = make_float4(0.f, 0.f, 0.f, 0.f);
        float4* o4 = reinterpret_cast<float4*>(out + (size_t)b * BS * GSZ);
        for (int k = l; k < BS * GSZ / 4; k += 192) o4[k] = z;
    } else {
        // ---- wave0: exact LAP on cost = -P, all state in registers ----
        const int jAcol = t + 1, jBcol = t + 65;
        double uA = 0.0, uB = 0.0, vA, vB;

        // column reduction seed: v[j] = min_i cost = -(max_i P); greedy assign
        {
            float cmA = Mf[t];      int raA = 0;
            float cmB = Mf[t + 64]; int raB = 0;
            for (int r = 1; r < BS; ++r) {
                float xA = Mf[r * (BS + 1) + t];
                if (xA > cmA) { cmA = xA; raA = r; }
                float xB = Mf[r * (BS + 1) + t + 64];
                if (xB > cmB) { cmB = xB; raB = r; }
            }
            vA = -(double)cmA; vB = -(double)cmB;
            rowasg[t] = 0x7FFFFFFF; rowasg[t + 64] = 0x7FFFFFFF;
            __threadfence_block();
            atomicMin(&rowasg[raA], jAcol);
            atomicMin(&rowasg[raB], jBcol);
            __threadfence_block();
            pA = (rowasg[raA] == jAcol) ? raA + 1 : 0;
            pB = (rowasg[raB] == jBcol) ? raB + 1 : 0;
        }

        // unassigned-row masks (rows 1..64 in un0, 65..128 in un1)
        unsigned long long un0 = __ballot(rowasg[t]      == 0x7FFFFFFF);
        unsigned long long un1 = __ballot(rowasg[t + 64] == 0x7FFFFFFF);

        // ---- ARR: augmenting row reduction (lapjv), capped — R4-verified.
        // Keeps v non-increasing (free rows stay feasible at u=0); winners
        // assigned tight (u=u2, v[j1] -= u2-u1). Dijkstra finishes exactly.
        for (int steps = 0; (un0 | un1) && steps < 512; ++steps) {
            int i;
            if (un0) i = __builtin_ctzll(un0) + 1;
            else     i = __builtin_ctzll(un1) + 65;

            double dA = -(double)Mf[(i - 1) * (BS + 1) + t]      - vA;
            double dB = -(double)Mf[(i - 1) * (BS + 1) + t + 64] - vB;
            unsigned long long kA = pkeyc(dA, jAcol), kB = pkeyc(dB, jBcol);

            unsigned long long k1 = wave_min_key(kA < kB ? kA : kB);
            const int  j1  = (int)(k1 & 0xFFull);
            const int  sl1 = (j1 - 1) & 63;
            const bool h1  = j1 > 64;
            double u1 = rl64(h1 ? dB : dA, sl1);

            unsigned long long kA2 = (jAcol == j1) ? ~0ull : kA;
            unsigned long long kB2 = (jBcol == j1) ? ~0ull : kB;
            unsigned long long k2 = wave_min_key(kA2 < kB2 ? kA2 : kB2);
            const int  sl2 = ((int)(k2 & 0xFFull) - 1) & 63;
            const bool h2  = (int)(k2 & 0xFFull) > 64;
            double u2 = rl64(h2 ? dB : dA, sl2);

            int i1 = rl32(h1 ? pB : pA, sl1);   // previous owner of j1 (0 = none)

            if (t == sl1) {
                if (h1) { pB = i; uB = u2; if (u1 < u2) vB -= (u2 - u1); }
                else    { pA = i; uA = u2; if (u1 < u2) vA -= (u2 - u1); }
            }
            if (i <= 64) un0 &= ~(1ull << (i - 1)); else un1 &= ~(1ull << (i - 65));
            if (i1 > 0) {
                if (i1 <= 64) un0 |= 1ull << (i1 - 1); else un1 |= 1ull << (i1 - 65);
            }
        }

        // ---- single-source Dijkstra phases (R4-verified recursion, pj-in-key) ----
        while (un0 | un1) {
            int i;
            if (un0) { int r = __builtin_ctzll(un0); un0 &= un0 - 1; i = r + 1; }
            else     { int r = __builtin_ctzll(un1); un1 &= un1 - 1; i = r + 65; }

            bool usedA = false, usedB = false;
            double mA = 1e18, mB = 1e18, SUM = 0.0;   // stored m = true_minv + SUM
            unsigned long long keyA = ~0ull, keyB = ~0ull;
            int wayA = 0, wayB = 0;
            int i0 = i, j0 = 0;
            double ui0 = 0.0;                          // free row: u = 0

            for (int guard = 0; guard <= BS + 2; ++guard) {
                // scan row i0 against this lane's two columns
                float cAv = Mf[(i0 - 1) * (BS + 1) + t];
                float cBv = Mf[(i0 - 1) * (BS + 1) + t + 64];
                if (!usedA) {
                    double nd = (-(double)cAv - ui0 - vA) + SUM;
                    if (nd < mA) { mA = nd; wayA = j0; keyA = pkey16(nd, pA, jAcol); }
                }
                if (!usedB) {
                    double nd = (-(double)cBv - ui0 - vB) + SUM;
                    if (nd < mB) { mB = nd; wayB = j0; keyB = pkey16(nd, pB, jBcol); }
                }
                unsigned long long kw = wave_min_key(keyA < keyB ? keyA : keyB);
                if (kw == ~0ull) break;                  // safety: fail visibly
                const int  j1 = (int)(kw & 0xFFull);
                const int  pj = (int)((kw >> 8) & 0xFFull);
                const int  sl = (j1 - 1) & 63;
                const bool hb = j1 > 64;

                double m_win = rl64(hb ? mB : mA, sl);   // exact f64 min value
                double delta = m_win - SUM;
                SUM = m_win;
                if (usedA) { uA += delta; vA -= delta; }
                if (usedB) { uB += delta; vB -= delta; }

                j0 = j1;
                if (pj == 0) break;                      // free column: augment
                ui0 = rl64(hb ? uB : uA, sl);            // owner u (pre-mark)
                i0 = pj;
                if (t == sl) { if (hb) { usedB = true; keyB = ~0ull; }
                               else    { usedA = true; keyA = ~0ull; } }
            }

            // augment along way-chain; duals u travel with their rows
            int jc = j0;
            for (int guard = 0; guard <= BS + 2; ++guard) {
                const int  slc = (jc - 1) & 63;
                const bool hc  = jc > 64;
                int jp = rl32(hc ? wayB : wayA, slc);
                int nprow; double nu;
                if (jp == 0) { nprow = i; nu = SUM; }    // start row: u was 0
                else {
                    const int  slp = (jp - 1) & 63;
                    const bool hp  = jp > 64;
                    nprow = rl32(hp ? pB : pA, slp);
                    nu    = rl64(hp ? uB : uA, slp);
                }
                if (!hc) { if (t == slc) { pA = nprow; uA = nu; } }
                else     { if (t == slc) { pB = nprow; uB = nu; } }
                if (jp == 0) break;
                jc = jp;
            }
        }
    }

    __syncthreads();   // stripe fully zeroed, assignment final

    if (t < 64) {
        const size_t base = (size_t)b * BS;
        if (pA >= 1) out[(base + (size_t)(pA - 1)) * GSZ + base + t]      = 1.0f;
        if (pB >= 1) out[(base + (size_t)(pB - 1)) * GSZ + base + t + 64] = 1.0f;
    }
}

extern "C" void kernel_launch(void* const* d_in, const int* in_sizes, int n_in,
                              void* d_out, int out_size, void* d_ws, size_t ws_size,
                              hipStream_t stream) {
    const float* w     = (const float*)d_in[0];
    const float* scale = (const float*)d_in[1];
    float* out = (float*)d_out;
    k_fused<<<NBLK, 256, 0, stream>>>(w, scale, out);
}